// Round 5
// baseline (4349.480 us; speedup 1.0000x reference)
//
#include <hip/hip_runtime.h>

typedef __attribute__((ext_vector_type(8))) short bf16x8;
typedef __attribute__((ext_vector_type(4))) float f32x4;
typedef __attribute__((ext_vector_type(4))) int i32x4;

#define Tn 1024
#define Bn 64
#define Hn 2048
#define NBLK 256
#define NTHR 512

// R16: TWO independent rings (batch rows never mix in a GRU). Ring R owns
// batch rows [32R, 32R+32); within a ring, 128 col-blocks.
// blockIdx.x -> R = bid & 1, c = bid >> 1 (rings interleave across XCDs).
//
// Dataflow ready counters: one line per (ring, consumer-leaf, K-slice-group).
// 2 rings x 16 leaves x 8 groups = 256 counters, each on its own 128B line
// (32 KB ctrl). R17: replica (R, leaf, g) is bumped TWICE per step per
// producer block (by wave 0 and wave 1, each right after its own store
// drain); value == 32*(t+1) means ring R's h_{t+1} slice g (both mt stripes)
// is fully at MALL. Consumers: wave w of col-block c polls (R, c>>3, w) ->
// 8 pollers/line (R12 lesson: >100 RMW pollers on ONE line serialize).
#define GRP(ring, leaf, g) (((((ring) << 7) | ((leaf) << 3) | (g))) * 32)

// watchdog: bounded spin so a liveness bug degrades to a wrong answer
// (diagnosable absmax failure) instead of a container-killing hang
#define SPIN_LIMIT (1u << 25)

__device__ __forceinline__ unsigned short f2b(float x) {
    // fp32 -> bf16 round-to-nearest-even
    unsigned u = __float_as_uint(x);
    return (unsigned short)((u + 0x7fffu + ((u >> 16) & 1u)) >> 16);
}
__device__ __forceinline__ float sigm(float x) {
    return __builtin_amdgcn_rcpf(1.0f + __expf(-x));
}
__device__ __forceinline__ float tanh_f(float x) {
    float e = __expf(2.0f * x);
    return 1.0f - 2.0f * __builtin_amdgcn_rcpf(1.0f + e);
}

// write-through system-scope stores: at MALL once vmcnt retires
__device__ __forceinline__ void store_short_wt(unsigned short* p, unsigned v) {
    asm volatile("global_store_short %0, %1, off sc0 sc1" :: "v"(p), "v"(v) : "memory");
}
__device__ __forceinline__ void store_dword_wt(float* p, float v) {
    asm volatile("global_store_dword %0, %1, off sc0 sc1" :: "v"(p), "v"(__float_as_uint(v)) : "memory");
}
__device__ __forceinline__ void store_u64_wt(unsigned long long* p, unsigned long long v) {
    asm volatile("global_store_dwordx2 %0, %1, off sc0 sc1" :: "v"(p), "v"(v) : "memory");
}
// Poll via atomic RMW(+0): the ONLY read primitive proven promptly coherent
// cross-XCD for ATOMICALLY-updated lines (R1-R6 ablation). asm because
// InstCombine turns fetch_add(p,0) back into a plain atomic load.
__device__ __forceinline__ unsigned poll_read(unsigned* p) {
    unsigned old;
    asm volatile("global_atomic_add %0, %1, %2, off sc0 sc1\n\ts_waitcnt vmcnt(0)"
                 : "=v"(old) : "v"(p), "v"(0u) : "memory");
    return old;
}

// h fragment layout (GLOBAL, shared by both rings; each ring touches only its
// own mt stripes): h_f[kk][mt][laneF][e], kk=k>>5, mt=b>>4,
// laneF=((k>>3)&3)*16+(b&15), e=k&7. One MFMA A-frag = 64 lanes x 16B contig.
__device__ __forceinline__ long hfrag_off(int b, int k) {
    return ((long)(((k >> 5) * 4 + (b >> 4)) * 64) + ((k >> 3) & 3) * 16 + (b & 15)) * 8 + (k & 7);
}

// Prep: init_hidden fp32 -> bf16 h0 (frag layout, WT stores so the MALL copy
// is authoritative for gru's bypass loads); zero ready counters (WT too).
__global__ void prep_kernel(const float* __restrict__ init_h,
                            unsigned short* __restrict__ h0,
                            unsigned* __restrict__ ctrl) {
    const int i = blockIdx.x * 256 + threadIdx.x;  // 0..32767
    const int b  = i >> 9;
    const int k4 = (i & 511) << 2;
    float4 v = *reinterpret_cast<const float4*>(init_h + (long)b * Hn + k4);
    unsigned long long q = (unsigned long long)f2b(v.x)
                         | ((unsigned long long)f2b(v.y) << 16)
                         | ((unsigned long long)f2b(v.z) << 32)
                         | ((unsigned long long)f2b(v.w) << 48);
    store_u64_wt((unsigned long long*)(h0 + hfrag_off(b, k4)), q);
    if (i < 8192)
        asm volatile("global_store_dword %0, %1, off sc0 sc1"
                     :: "v"(ctrl + i), "v"(0u) : "memory");
}

// Persistent GRU. 256 blocks x 512 threads (8 waves) = 1 block/CU, all CUs.
// Ring R (bid&1) owns batch rows [32R,32R+32); col-block c (bid>>1) owns 16
// hidden units j in [16c, 16c+16). Wave w owns K-slice [256w, 256w+256);
// W rows live in REGISTERS (Bf[3][8]).
//
// Ledger: R13 dataflow flags (-11%). R14 REVERTED (x loads stay BEFORE the
//   poll; LDS reduce stays batched -- merging per-ELEMENT serializes; batched
//   read-then-write fusion is fine and used below). R15 setprio: null, kept.
//   R16 batch-split 2 rings, one burst (-23%). Calibration from R16: step =
//   9600cy with ~2000cy compute -> exposed MALL RTT ~1500cy each, 4-5 on the
//   ring cycle. Each removed/overlapped RTT ~= 0.65us.
// R17 (this): overlap producer tail with consumer head.
//   (1) red[] parity-double-buffered (24->48KB): waves 4-7's t+1 round-1
//       writes can't WAR waves 0-1's t reads -> sync4 DELETED. Waves 2-7 run
//       ahead into t+1's poll/load/MFMA while waves 0-1 finish t's epilogue.
//   (2) barriers 4->2: round-2 is wave-local (read bucket w, add, write
//       bucket w) when BATCHED (6 reads, then 6 add+writes) -> sync2/3
//       collapse into one sync_b. Every wave executes exactly 2 barriers
//       per iteration (uniform phasing).
//   (3) waves 0 and 1 each drain their OWN stores then bump immediately
//       (16 replica lines each, one atomic instr); counter target 32t.
//       The signal no longer waits for a block-wide rendezvous.
//
// Buffer-reuse safety WITHOUT any block-wide post-store barrier: every
// wave's h_t loads complete (vmcnt0, asm-tied) before it reaches sync_a(t);
// bumps(t) are after sync_b(t) > sync_a(t); a producer stores h_{t+2} only
// after its 8 waves detect 32(t+1), which needs EVERY block's bumps(t) ->
// transitively after every consumer's h_t loads. Skew < 2 steps,
// deadlock-free (all 256 blocks co-resident: 1 block/CU, 48KB LDS, 8 waves).
//
// K-loop: 1 ASM-PINNED burst of 16x global_load_dwordx4 sc0/sc1 followed by
// a single s_waitcnt vmcnt(0) carrying the 16 buffers as "+v" operands
// (dataflow ties the MFMAs to the waitcnt -> no hoist hazard).
// NO fences / cache maintenance in the hot loop (R5). All signals via RMW,
// all polls via RMW(+0).
__global__ void __launch_bounds__(NTHR, 2) gru_kernel(
    const float* __restrict__ inp,     // [T][B][3]
    const float* __restrict__ init_h,  // [B][H]
    const float* __restrict__ w_ih,    // [3H][3]
    const float* __restrict__ w_hh,    // [3H][H] fp32
    const float* __restrict__ bias,    // [3H]
    const float* __restrict__ bias_n,  // [H]
    unsigned short* __restrict__ h0,   // [B][H] bf16 frag-layout double buffer
    unsigned short* __restrict__ h1,
    unsigned* __restrict__ ctrl,       // [8192] ready counters (256 lines)
    float* __restrict__ out)           // [T][B]
{
    __shared__ f32x4 red[2][4][2][3][64];  // [parity][bucket][m][nt][lane] = 48 KB

    const int tid  = threadIdx.x;
    const int lane = tid & 63;
    const int w    = tid >> 6;      // wave id = K-slice owner
    const int quad = lane >> 4;
    const int n16  = lane & 15;
    const int R    = blockIdx.x & 1;        // ring id (batch half)
    const int c    = blockIdx.x >> 1;       // col-block id 0..127
    const int jg   = c * 16 + n16;  // this lane's hidden column (epilogue)
    const int ks   = w * 256;
    const int bbase = 32 * R;       // ring's batch base

    // ---- preload W rows into registers as bf16 B-fragments (one-time) ----
    bf16x8 Bf[3][8];
    #pragma unroll
    for (int nt = 0; nt < 3; ++nt) {
        const long row = (long)(nt * Hn + jg);
        #pragma unroll
        for (int k = 0; k < 8; ++k) {
            const float* p = w_hh + row * Hn + ks + k * 32 + quad * 8;
            bf16x8 b;
            #pragma unroll
            for (int j = 0; j < 8; ++j) b[j] = (short)f2b(p[j]);
            Bf[nt][k] = b;
        }
    }

    // Epilogue constants (used by waves 0-1; all 64 lanes active)
    float wr0 = w_ih[jg*3+0], wr1 = w_ih[jg*3+1], wr2 = w_ih[jg*3+2];
    float wz0 = w_ih[(Hn+jg)*3+0], wz1 = w_ih[(Hn+jg)*3+1], wz2 = w_ih[(Hn+jg)*3+2];
    float wn0 = w_ih[(2*Hn+jg)*3+0], wn1 = w_ih[(2*Hn+jg)*3+1], wn2 = w_ih[(2*Hn+jg)*3+2];
    float br_ = bias[jg], bz_ = bias[Hn+jg], bn2_ = bias[2*Hn+jg];
    float bnn_ = bias_n[jg];

    // fp32 hidden state (waves 0-1; batch b = bbase + 16w + quad*4 + r, col jg)
    float hst[4];
    if (w < 2) {
        #pragma unroll
        for (int r = 0; r < 4; ++r)
            hst[r] = init_h[(long)(bbase + 16 * w + quad * 4 + r) * Hn + jg];
    }

    // epilogue frag-store decomposition of j = 16c + n16 (mt = 2R + w)
    const int kkE = c >> 1;                     // j>>5 (lane-uniform)
    const int qE  = (c & 1) * 2 + (n16 >> 3);
    const int eE  = n16 & 7;

    const int leafC = c >> 3;          // consumer replica index (per ring)
    const int grp   = c >> 4;          // K-slice group we produce (per ring)

    for (int t = 0; t < Tn; ++t) {
        const unsigned short* hcur = (t & 1) ? h1 : h0;
        unsigned short* hnext      = (t & 1) ? h0 : h1;
        f32x4 (*redp)[2][3][64] = red[t & 1];   // parity LDS buffer

        // input contributions for this step. Issued BEFORE the poll: their
        // HBM/MALL RTT hides entirely under the poll's own atomic RTT
        // (R14 lesson: any other placement puts them on the critical path).
        float xv[4][3];
        if (w < 2) {
            #pragma unroll
            for (int r = 0; r < 4; ++r) {
                const float* xp = inp + ((long)t * Bn + bbase + 16 * w + quad * 4 + r) * 3;
                xv[r][0] = xp[0]; xv[r][1] = xp[1]; xv[r][2] = xp[2];
            }
        }

        f32x4 acc[2][3];
        #pragma unroll
        for (int m = 0; m < 2; ++m)
            #pragma unroll
            for (int nt = 0; nt < 3; ++nt)
                acc[m][nt] = f32x4{0.f, 0.f, 0.f, 0.f};

        // ---- dataflow wait: THIS wave's K-slice (this ring) at MALL? ----
        // lane 0 spins, wave reconverges; volatile-asm ordering keeps the
        // h-burst loads below from hoisting above the poll. Target 32t:
        // 16 producers x 2 per-wave bumps per step.
        if (lane == 0 && t) {
            const unsigned tgt = (unsigned)(t << 5);   // 32*t
            unsigned spins = 0;
            while (poll_read(&ctrl[GRP(R, leafC, w)]) < tgt) {
                __builtin_amdgcn_s_sleep(1);
                if (++spins > SPIN_LIMIT) break;   // watchdog
            }
        }

        // wave's A-frag base: frag f = 32w + 4*kki + 2R + m, at short-offset
        // f*512 + lane*8 (this ring's two mt stripes of the wave's kk range)
        const unsigned short* pa = hcur + ((long)(32 * w + 2 * R) * 64 + lane) * 8;

        // ---- 1 asm-pinned burst: 16x dwordx4 loads, waitcnt, 48 MFMAs ----
        i32x4 hb[16];
        #pragma unroll
        for (int kki = 0; kki < 8; ++kki) {
            #pragma unroll
            for (int m = 0; m < 2; ++m) {
                asm volatile("global_load_dwordx4 %0, %1, off sc0 sc1"
                             : "=v"(hb[kki * 2 + m])
                             : "v"(pa + (long)(kki * 4 + m) * 512) : "memory");
            }
        }
        asm volatile("s_waitcnt vmcnt(0)"
                     : "+v"(hb[0]), "+v"(hb[1]), "+v"(hb[2]), "+v"(hb[3]),
                       "+v"(hb[4]), "+v"(hb[5]), "+v"(hb[6]), "+v"(hb[7]),
                       "+v"(hb[8]), "+v"(hb[9]), "+v"(hb[10]), "+v"(hb[11]),
                       "+v"(hb[12]), "+v"(hb[13]), "+v"(hb[14]), "+v"(hb[15])
                     :: "memory");
        // T5: prioritize the MFMA-issuing wave over co-resident waves that
        // are spinning in polls / issuing loads (kept from R15; noise-level).
        __builtin_amdgcn_s_setprio(1);
        #pragma unroll
        for (int kki = 0; kki < 8; ++kki) {
            #pragma unroll
            for (int m = 0; m < 2; ++m) {
                union { i32x4 q; bf16x8 v; } u;
                u.q = hb[kki * 2 + m];
                bf16x8 a = u.v;
                acc[m][0] = __builtin_amdgcn_mfma_f32_16x16x32_bf16(a, Bf[0][kki], acc[m][0], 0, 0, 0);
                acc[m][1] = __builtin_amdgcn_mfma_f32_16x16x32_bf16(a, Bf[1][kki], acc[m][1], 0, 0, 0);
                acc[m][2] = __builtin_amdgcn_mfma_f32_16x16x32_bf16(a, Bf[2][kki], acc[m][2], 0, 0, 0);
            }
        }
        __builtin_amdgcn_s_setprio(0);

        // ---- cross-wave K reduction through parity LDS (2 barriers) ----
        // Round 1: waves 4-7 publish into bucket (w-4) of THIS parity.
        if (w >= 4) {
            #pragma unroll
            for (int m = 0; m < 2; ++m)
                #pragma unroll
                for (int nt = 0; nt < 3; ++nt)
                    redp[w - 4][m][nt][lane] = acc[m][nt];
        }
        __syncthreads();   // sync_a
        // Round 2 (waves 0-3): wave-local bucket w. BATCHED: 6 reads first,
        // then 6 add+writes (R14 lesson: per-element interleave serializes
        // 12 LDS round-trips; batched fusion is fine, needs no barrier).
        if (w < 4) {
            f32x4 tmp[2][3];
            #pragma unroll
            for (int m = 0; m < 2; ++m)
                #pragma unroll
                for (int nt = 0; nt < 3; ++nt)
                    tmp[m][nt] = redp[w][m][nt][lane];
            #pragma unroll
            for (int m = 0; m < 2; ++m)
                #pragma unroll
                for (int nt = 0; nt < 3; ++nt)
                    redp[w][m][nt][lane] = acc[m][nt] + tmp[m][nt];
        }
        __syncthreads();   // sync_b  (waves 2-7 now run ahead into t+1)

        if (w < 2) {
            f32x4 s0 = redp[0][w][0][lane], s1 = redp[0][w][1][lane], s2 = redp[0][w][2][lane];
            #pragma unroll
            for (int src = 1; src < 4; ++src) {
                s0 += redp[src][w][0][lane];
                s1 += redp[src][w][1][lane];
                s2 += redp[src][w][2][lane];
            }
            #pragma unroll
            for (int r = 0; r < 4; ++r) {
                const int b = bbase + 16 * w + quad * 4 + r;
                float pr = br_ + wr0*xv[r][0] + wr1*xv[r][1] + wr2*xv[r][2] + s0[r];
                float pz = bz_ + wz0*xv[r][0] + wz1*xv[r][1] + wz2*xv[r][2] + s1[r];
                float rr = sigm(pr);
                float zz = sigm(pz);
                float pn = bn2_ + wn0*xv[r][0] + wn1*xv[r][1] + wn2*xv[r][2] + rr * (s2[r] + bnn_);
                float nn = tanh_f(pn);
                float hv = nn + zz * (hst[r] - nn);
                hst[r] = hv;
                store_short_wt(hnext + ((long)((kkE * 4 + 2 * R + w) * 64) + qE * 16 + quad * 4 + r) * 8 + eE,
                               (unsigned)f2b(hv));
                if (c == 0 && n16 == 0)
                    store_dword_wt(out + t * Bn + b, hv);
            }
            // ---- per-wave producer signal: drain OWN stores, then bump the
            // 16 leaf replicas of our group's counter (16 lanes, one atomic
            // instr, 16 distinct lines). No block-wide rendezvous on the
            // signal path: waves 0 and 1 each contribute one bump -> 32/step.
            asm volatile("s_waitcnt vmcnt(0)" ::: "memory");  // stores at MALL
            if (lane < 16)
                __hip_atomic_fetch_add(&ctrl[GRP(R, lane, grp)], 1u,
                                       __ATOMIC_RELAXED, __HIP_MEMORY_SCOPE_SYSTEM);
        }
        // no loop-end barrier: red[] parity removes the WAR hazard; h-buffer
        // reuse is ordered through the flag protocol (see header proof).
    }
}

extern "C" void kernel_launch(void* const* d_in, const int* in_sizes, int n_in,
                              void* d_out, int out_size, void* d_ws, size_t ws_size,
                              hipStream_t stream) {
    const float* inp    = (const float*)d_in[0];  // [1024][64][3]
    const float* init_h = (const float*)d_in[1];  // [64][2048]
    const float* w_ih   = (const float*)d_in[2];  // [6144][3]
    const float* w_hh   = (const float*)d_in[3];  // [6144][2048]
    const float* bias   = (const float*)d_in[4];  // [6144]
    const float* bias_n = (const float*)d_in[5];  // [2048]
    float* out = (float*)d_out;                   // [1024][64]

    unsigned short* h0 = (unsigned short*)d_ws;          // 262144 B
    unsigned short* h1 = h0 + 131072L;                   // 262144 B
    unsigned* ctrl     = (unsigned*)(h1 + 131072L);      // 32768 B

    prep_kernel<<<128, 256, 0, stream>>>(init_h, h0, ctrl);
    gru_kernel<<<NBLK, NTHR, 0, stream>>>(inp, init_h, w_ih, w_hh, bias, bias_n,
                                          h0, h1, ctrl, out);
}